// Round 6
// baseline (3103.489 us; speedup 1.0000x reference)
//
#include <hip/hip_runtime.h>
#include <stdint.h>

#define NPTS 8192
#define KNN 32
#define KPN 15
#define SCC 64
#define OUTC 256
#define R2F 0.0144f
#define INV_EXT (1.0f/0.096f)

// ---- conv_in: one thread per (cloud,n,c); h[cloud][n][c] f32 -----------------
__global__ __launch_bounds__(256) void conv_in_naive(
    const float* __restrict__ src, const float* __restrict__ tgt,
    const float* __restrict__ W, const float* __restrict__ b,
    float* __restrict__ h)
{
  size_t e = (size_t)blockIdx.x*256 + threadIdx.x;   // < 2*8192*64 = 2^20
  int c = (int)(e & 63);
  int n = (int)((e >> 6) & 8191);
  int cloud = (int)(e >> 19);
  const float* x = cloud ? tgt : src;
  float acc = b[c];
  const float* xr = x + (size_t)n*256;
  for (int k = 0; k < 256; ++k)
    acc = fmaf(xr[k], W[(size_t)k*64 + c], acc);
  h[e] = acc;
}

// ---- kNN: one thread per query, stream all 8192 candidates -------------------
// key = (f32 bits of d2)<<32 | idx  -> u64 min == (d2, idx) lexicographic
__global__ __launch_bounds__(128) void knn_naive(
    const float* __restrict__ cA, const float* __restrict__ cB,
    int* __restrict__ fidx)
{
  __shared__ unsigned long long lst[KNN][128];   // 32 KB
  int t = threadIdx.x;
  int g = blockIdx.x*128 + t;        // 0..16383
  int cloud = g >> 13, q = g & 8191;
  const float* coords = cloud ? cB : cA;
  float qx = coords[(size_t)q*3];
  float qy = coords[(size_t)q*3+1];
  float qz = coords[(size_t)q*3+2];
  #pragma unroll
  for (int s = 0; s < KNN; ++s) lst[s][t] = ~0ULL;
  unsigned long long curmax = ~0ULL;
  int maxslot = 0;
  for (int i = 0; i < NPTS; ++i) {
    float dx = qx - coords[(size_t)i*3];
    float dy = qy - coords[(size_t)i*3+1];
    float dz = qz - coords[(size_t)i*3+2];
    float d2 = fmaf(dx, dx, fmaf(dy, dy, dz*dz));
    if (d2 <= R2F) {   // beyond radius -> influence exactly 0 in reference
      unsigned long long key =
          ((unsigned long long)__float_as_uint(d2) << 32) | (unsigned int)i;
      if (key < curmax) {
        lst[maxslot][t] = key;
        unsigned long long m = lst[0][t]; int ms = 0;
        #pragma unroll
        for (int s = 1; s < KNN; ++s) {
          unsigned long long v = lst[s][t];
          if (v > m) { m = v; ms = s; }
        }
        curmax = m; maxslot = ms;
      }
    }
  }
  #pragma unroll
  for (int s = 0; s < KNN; ++s)
    fidx[((size_t)(cloud*NPTS + q))*KNN + s] = (int)(lst[s][t] & 0xffffffffu);
}

// ---- fused KPConv: per block one point; agg in LDS; contract with W_kp -------
// h2[n][d] = sum_{p,c} (sum_k infl[k][p] * h[nb_k][c]) * W_kp[p][c][d]
__global__ __launch_bounds__(64) void kpconv_fused(
    const float* __restrict__ cA, const float* __restrict__ cB,
    const float* __restrict__ kpts, const int* __restrict__ fidx,
    const float* __restrict__ h, const float* __restrict__ Wkp,
    float* __restrict__ h2)
{
  __shared__ float w_s[KNN][KPN];     // [32][15]
  __shared__ float agg_s[KPN*SCC];    // [15*64] flat, j = p*64+c
  __shared__ int   idx_s[KNN];
  int b = blockIdx.x;                 // 0..16383
  int cloud = b >> 13, n = b & 8191;
  int t = threadIdx.x;                // 0..63
  const float* coords = cloud ? cB : cA;
  if (t < KNN) idx_s[t] = fidx[((size_t)(cloud*NPTS + n))*KNN + t];
  __syncthreads();
  float qx = coords[(size_t)n*3];
  float qy = coords[(size_t)n*3+1];
  float qz = coords[(size_t)n*3+2];
  for (int e = t; e < KNN*KPN; e += 64) {
    int k = e / KPN, p = e % KPN;
    int idx = idx_s[k];
    float w = 0.f;
    if (idx >= 0) {
      float rx = coords[(size_t)idx*3]   - qx;
      float ry = coords[(size_t)idx*3+1] - qy;
      float rz = coords[(size_t)idx*3+2] - qz;
      float dx = rx - kpts[(size_t)p*3];
      float dy = ry - kpts[(size_t)p*3+1];
      float dz = rz - kpts[(size_t)p*3+2];
      float d = sqrtf(fmaf(dx, dx, fmaf(dy, dy, dz*dz)));
      w = fmaxf(1.0f - d*INV_EXT, 0.0f);
    }
    w_s[k][p] = w;
  }
  __syncthreads();
  // accumulate agg[p][c] for c = t
  float acc[KPN];
  #pragma unroll
  for (int p = 0; p < KPN; ++p) acc[p] = 0.f;
  for (int k = 0; k < KNN; ++k) {
    int idx = idx_s[k];                 // wave-uniform
    if (idx < 0) continue;
    float f = h[((size_t)(cloud*NPTS + idx))*SCC + t];
    #pragma unroll
    for (int p = 0; p < KPN; ++p) acc[p] = fmaf(w_s[k][p], f, acc[p]);
  }
  #pragma unroll
  for (int p = 0; p < KPN; ++p) agg_s[p*SCC + t] = acc[p];
  __syncthreads();
  // contract: out[d=t] = sum_j agg[j] * Wkp[j*64 + t],  j = p*64+c
  float out = 0.f;
  for (int j = 0; j < KPN*SCC; ++j)
    out = fmaf(agg_s[j], Wkp[(size_t)j*SCC + t], out);
  h2[((size_t)(cloud*NPTS + n))*SCC + t] = out;
}

// ---- conv_out: one thread per (cloud,n,d), f32 out ---------------------------
__global__ __launch_bounds__(256) void conv_out_naive(
    const float* __restrict__ h2, const float* __restrict__ W,
    const float* __restrict__ b, float* __restrict__ y)
{
  size_t e = (size_t)blockIdx.x*256 + threadIdx.x;   // < 2*8192*256 = 2^22
  int d = (int)(e & 255);
  size_t nrow = e >> 8;            // cloud*8192 + n
  float acc = b[d];
  const float* hr = h2 + nrow*SCC;
  for (int c = 0; c < SCC; ++c)
    acc = fmaf(hr[c], W[(size_t)c*256 + d], acc);
  y[e] = acc;
}

// ---- BN ----------------------------------------------------------------------
__global__ void zero_stats(float* __restrict__ s) {
  s[blockIdx.x*256 + threadIdx.x] = 0.f;
}

__global__ __launch_bounds__(256) void bn_stats_k(
    const float* __restrict__ y, float* __restrict__ stats)
{
  int b = blockIdx.x;          // 64 blocks
  int cloud = b >> 5, rb = b & 31;
  int c = threadIdx.x;
  size_t base = ((size_t)(cloud*NPTS + rb*256))*OUTC + c;
  float s = 0.f, s2 = 0.f;
  for (int r = 0; r < 256; ++r) {
    float v = y[base + (size_t)r*OUTC];
    s += v; s2 = fmaf(v, v, s2);
  }
  atomicAdd(&stats[cloud*512 + c], s);
  atomicAdd(&stats[cloud*512 + 256 + c], s2);
}

__global__ __launch_bounds__(256) void bn_apply_k(
    float* __restrict__ y, const float* __restrict__ stats,
    const float* __restrict__ gamma, const float* __restrict__ beta)
{
  size_t e = (size_t)blockIdx.x*256 + threadIdx.x;
  int c = (int)(e & 255);
  int cloud = (int)(e >> 21);
  float s  = stats[cloud*512 + c];
  float s2 = stats[cloud*512 + 256 + c];
  float mu  = s * (1.0f/NPTS);
  float var = fmaxf(s2 * (1.0f/NPTS) - mu*mu, 0.f);
  float sc = gamma[c] * rsqrtf(var + 1e-5f);
  float sh = beta[c] - mu*sc;
  float v = fmaf(y[e], sc, sh);
  v = v > 0.f ? v : 0.1f*v;
  y[e] = v;
}

// ---- coords tail of output (f32) --------------------------------------------
__global__ __launch_bounds__(256) void emit_coords(
    const float* __restrict__ scd, const float* __restrict__ tcd,
    float* __restrict__ out)
{
  int i = blockIdx.x*256 + threadIdx.x;    // 0..49151
  out[i] = (i < NPTS*3) ? scd[i] : tcd[i - NPTS*3];
}

extern "C" void kernel_launch(void* const* d_in, const int* in_sizes, int n_in,
                              void* d_out, int out_size, void* d_ws, size_t ws_size,
                              hipStream_t stream)
{
  (void)in_sizes; (void)n_in; (void)out_size; (void)ws_size;
  const float* src   = (const float*)d_in[0];
  const float* tgt   = (const float*)d_in[1];
  const float* scd   = (const float*)d_in[2];
  const float* tcd   = (const float*)d_in[3];
  const float* W_in  = (const float*)d_in[4];
  const float* b_in  = (const float*)d_in[5];
  const float* kpts  = (const float*)d_in[6];
  const float* W_kp  = (const float*)d_in[7];
  const float* W_out = (const float*)d_in[8];
  const float* b_out = (const float*)d_in[9];
  const float* gamma = (const float*)d_in[10];
  const float* beta  = (const float*)d_in[11];

  char* ws = (char*)d_ws;
  float* h     = (float*)ws;                        // 4 MB: [2][8192][64]
  float* h2    = (float*)(ws + (4u<<20));           // 4 MB
  int*   fidx  = (int*)(ws + (8u<<20));             // 2 MB
  float* stats = (float*)(ws + (10u<<20));          // 4 KB

  float* yout = (float*)d_out;

  conv_in_naive<<<4096, 256, 0, stream>>>(src, tgt, W_in, b_in, h);
  knn_naive<<<128, 128, 0, stream>>>(scd, tcd, fidx);
  kpconv_fused<<<16384, 64, 0, stream>>>(scd, tcd, kpts, fidx, h, W_kp, h2);
  conv_out_naive<<<16384, 256, 0, stream>>>(h2, W_out, b_out, yout);
  zero_stats<<<4, 256, 0, stream>>>(stats);
  bn_stats_k<<<64, 256, 0, stream>>>(yout, stats);
  bn_apply_k<<<16384, 256, 0, stream>>>(yout, stats, gamma, beta);
  emit_coords<<<192, 256, 0, stream>>>(scd, tcd, yout + (size_t)2*NPTS*OUTC);
}

// Round 9
// 906.575 us; speedup vs baseline: 3.4233x; 3.4233x over previous
//
#include <hip/hip_runtime.h>
#include <stdint.h>

#define NPTS 8192
#define KNN 32
#define KPN 15
#define SCC 64
#define OUTC 256
#define R2F 0.0144f              /* radius^2: the reference's in_range mask */
#define INV_EXT (1.0f/0.096f)
#define SLOTCAP 128

// NOTE (R8 lesson): influence uses distances to OFFSET kernel points
// (|kp| up to ~0.2), so neighbors with extent < d <= radius CAN contribute.
// The only valid candidate filter is the radius mask itself (d2 <= R2F).

// ---- generic zero -----------------------------------------------------------
__global__ void zero_u32(unsigned int* __restrict__ p, int n) {
  int i = blockIdx.x*256 + threadIdx.x;
  if (i < n) p[i] = 0u;
}

// ---- conv_in: one thread per (cloud,n,c); h[cloud][n][c] f32 -----------------
__global__ __launch_bounds__(256) void conv_in_naive(
    const float* __restrict__ src, const float* __restrict__ tgt,
    const float* __restrict__ W, const float* __restrict__ b,
    float* __restrict__ h)
{
  size_t e = (size_t)blockIdx.x*256 + threadIdx.x;   // < 2*8192*64 = 2^20
  int c = (int)(e & 63);
  int n = (int)((e >> 6) & 8191);
  int cloud = (int)(e >> 19);
  const float* x = cloud ? tgt : src;
  float acc = b[c];
  const float* xr = x + (size_t)n*256;
  for (int k = 0; k < 256; ++k)
    acc = fmaf(xr[k], W[(size_t)k*64 + c], acc);
  h[e] = acc;
}

// ---- kNN phase 1: gather indices of candidates with d2 <= radius^2 -----------
// Top-32-of-all == top-32-of-{d2<=R2F} because out-of-radius entries of the
// reference's top-32 get influence 0 (in_range mask). In-radius count is
// Poisson(lambda<=~59) -> P(>128) ~ 1e-19: SLOTCAP=128 never overflows.
__global__ __launch_bounds__(128) void knn_gather(
    const float* __restrict__ cA, const float* __restrict__ cB,
    unsigned int* __restrict__ cnt, unsigned short* __restrict__ slots)
{
  __shared__ float4 cand[2048];      // 32 KB
  int b = blockIdx.x;                // 512 blocks: cloud(1)|qb(6)|chunk(2)
  int cloud = b >> 8;
  int qb = (b >> 2) & 63;
  int chunk = b & 3;
  const float* coords = cloud ? cB : cA;
  int t = threadIdx.x;
  int q = qb*128 + t;
  int base = chunk*2048;
  for (int i = t; i < 2048; i += 128) {
    int j = base + i;
    cand[i] = make_float4(coords[(size_t)j*3], coords[(size_t)j*3+1],
                          coords[(size_t)j*3+2], 0.f);
  }
  float qx = coords[(size_t)q*3];
  float qy = coords[(size_t)q*3+1];
  float qz = coords[(size_t)q*3+2];
  __syncthreads();
  unsigned int* myc = &cnt[cloud*NPTS + q];
  unsigned short* myslot = &slots[((size_t)(cloud*NPTS + q))*SLOTCAP];
  #pragma unroll 4
  for (int i = 0; i < 2048; ++i) {
    float4 c = cand[i];
    float dx = qx - c.x, dy = qy - c.y, dz = qz - c.z;
    float d2 = fmaf(dx, dx, fmaf(dy, dy, dz*dz));
    if (d2 <= R2F) {
      unsigned int pos = atomicAdd(myc, 1u);
      if (pos < SLOTCAP)
        myslot[pos] = (unsigned short)(base + i);
    }
  }
}

// ---- kNN phase 2: top-32 (lex-smallest (d2,idx)) of gathered candidates ------
// Same insert-evict loop as the R6-proven knn_naive, but scanning <=128
// gathered indices instead of all 8192 points.
__global__ __launch_bounds__(64) void knn_select(
    const float* __restrict__ cA, const float* __restrict__ cB,
    const unsigned int* __restrict__ cnt,
    const unsigned short* __restrict__ slots, short* __restrict__ fidx)
{
  __shared__ unsigned long long lst[KNN][64];  // 16 KB, column-private
  int t = threadIdx.x;
  int g = blockIdx.x*64 + t;       // 0..16383 = cloud*NPTS + q
  int cloud = g >> 13, q = g & 8191;
  const float* coords = cloud ? cB : cA;
  float qx = coords[(size_t)q*3];
  float qy = coords[(size_t)q*3+1];
  float qz = coords[(size_t)q*3+2];
  unsigned int C = cnt[g]; if (C > SLOTCAP) C = SLOTCAP;
  const unsigned short* ms = &slots[(size_t)g*SLOTCAP];
  #pragma unroll
  for (int s = 0; s < KNN; ++s) lst[s][t] = ~0ULL;
  unsigned long long curmax = ~0ULL;
  int maxslot = 0;
  for (int j = 0; j < (int)C; ++j) {
    int ci = ms[j];
    float dx = qx - coords[(size_t)ci*3];
    float dy = qy - coords[(size_t)ci*3+1];
    float dz = qz - coords[(size_t)ci*3+2];
    float d2 = fmaf(dx, dx, fmaf(dy, dy, dz*dz));
    unsigned long long key =
        ((unsigned long long)__float_as_uint(d2) << 32) | (unsigned int)ci;
    if (key < curmax) {
      lst[maxslot][t] = key;
      unsigned long long m = lst[0][t]; int ms2 = 0;
      #pragma unroll
      for (int s = 1; s < KNN; ++s) {
        unsigned long long v = lst[s][t];
        if (v > m) { m = v; ms2 = s; }
      }
      curmax = m; maxslot = ms2;
    }
  }
  #pragma unroll
  for (int s = 0; s < KNN; ++s)
    fidx[(size_t)g*KNN + s] = (short)(lst[s][t] & 0xffffu); // 0xffff -> -1
}

// ---- fused KPConv: per block one point; agg in LDS; contract with W_kp -------
// h2[n][d] = sum_{p,c} (sum_k infl[k][p] * h[nb_k][c]) * W_kp[p][c][d]
__global__ __launch_bounds__(64) void kpconv_fused(
    const float* __restrict__ cA, const float* __restrict__ cB,
    const float* __restrict__ kpts, const short* __restrict__ fidx,
    const float* __restrict__ h, const float* __restrict__ Wkp,
    float* __restrict__ h2)
{
  __shared__ float w_s[KNN][KPN];     // [32][15]
  __shared__ float agg_s[KPN*SCC];    // [15*64] flat, j = p*64+c
  __shared__ int   idx_s[KNN];
  int b = blockIdx.x;                 // 0..16383
  int cloud = b >> 13, n = b & 8191;
  int t = threadIdx.x;                // 0..63
  const float* coords = cloud ? cB : cA;
  if (t < KNN) idx_s[t] = fidx[((size_t)(cloud*NPTS + n))*KNN + t];
  __syncthreads();
  float qx = coords[(size_t)n*3];
  float qy = coords[(size_t)n*3+1];
  float qz = coords[(size_t)n*3+2];
  for (int e = t; e < KNN*KPN; e += 64) {
    int k = e / KPN, p = e % KPN;
    int idx = idx_s[k];
    float w = 0.f;
    if (idx >= 0) {
      float rx = coords[(size_t)idx*3]   - qx;
      float ry = coords[(size_t)idx*3+1] - qy;
      float rz = coords[(size_t)idx*3+2] - qz;
      float dx = rx - kpts[(size_t)p*3];
      float dy = ry - kpts[(size_t)p*3+1];
      float dz = rz - kpts[(size_t)p*3+2];
      float d = sqrtf(fmaf(dx, dx, fmaf(dy, dy, dz*dz)));
      w = fmaxf(1.0f - d*INV_EXT, 0.0f);
    }
    w_s[k][p] = w;
  }
  __syncthreads();
  // accumulate agg[p][c] for c = t
  float acc[KPN];
  #pragma unroll
  for (int p = 0; p < KPN; ++p) acc[p] = 0.f;
  for (int k = 0; k < KNN; ++k) {
    int idx = idx_s[k];                 // wave-uniform
    if (idx < 0) continue;
    float f = h[((size_t)(cloud*NPTS + idx))*SCC + t];
    #pragma unroll
    for (int p = 0; p < KPN; ++p) acc[p] = fmaf(w_s[k][p], f, acc[p]);
  }
  #pragma unroll
  for (int p = 0; p < KPN; ++p) agg_s[p*SCC + t] = acc[p];
  __syncthreads();
  // contract: out[d=t] = sum_j agg[j] * Wkp[j*64 + t],  j = p*64+c
  float out = 0.f;
  for (int j = 0; j < KPN*SCC; ++j)
    out = fmaf(agg_s[j], Wkp[(size_t)j*SCC + t], out);
  h2[((size_t)(cloud*NPTS + n))*SCC + t] = out;
}

// ---- conv_out: one thread per (cloud,n,d), f32 out ---------------------------
__global__ __launch_bounds__(256) void conv_out_naive(
    const float* __restrict__ h2, const float* __restrict__ W,
    const float* __restrict__ b, float* __restrict__ y)
{
  size_t e = (size_t)blockIdx.x*256 + threadIdx.x;   // < 2*8192*256 = 2^22
  int d = (int)(e & 255);
  size_t nrow = e >> 8;            // cloud*8192 + n
  float acc = b[d];
  const float* hr = h2 + nrow*SCC;
  for (int c = 0; c < SCC; ++c)
    acc = fmaf(hr[c], W[(size_t)c*256 + d], acc);
  y[e] = acc;
}

// ---- BN ----------------------------------------------------------------------
__global__ __launch_bounds__(256) void bn_stats_k(
    const float* __restrict__ y, float* __restrict__ stats)
{
  int b = blockIdx.x;          // 64 blocks
  int cloud = b >> 5, rb = b & 31;
  int c = threadIdx.x;
  size_t base = ((size_t)(cloud*NPTS + rb*256))*OUTC + c;
  float s = 0.f, s2 = 0.f;
  for (int r = 0; r < 256; ++r) {
    float v = y[base + (size_t)r*OUTC];
    s += v; s2 = fmaf(v, v, s2);
  }
  atomicAdd(&stats[cloud*512 + c], s);
  atomicAdd(&stats[cloud*512 + 256 + c], s2);
}

__global__ __launch_bounds__(256) void bn_apply_k(
    float* __restrict__ y, const float* __restrict__ stats,
    const float* __restrict__ gamma, const float* __restrict__ beta)
{
  size_t e = (size_t)blockIdx.x*256 + threadIdx.x;
  int c = (int)(e & 255);
  int cloud = (int)(e >> 21);
  float s  = stats[cloud*512 + c];
  float s2 = stats[cloud*512 + 256 + c];
  float mu  = s * (1.0f/NPTS);
  float var = fmaxf(s2 * (1.0f/NPTS) - mu*mu, 0.f);
  float sc = gamma[c] * rsqrtf(var + 1e-5f);
  float sh = beta[c] - mu*sc;
  float v = fmaf(y[e], sc, sh);
  v = v > 0.f ? v : 0.1f*v;
  y[e] = v;
}

// ---- coords tail of output (f32) --------------------------------------------
__global__ __launch_bounds__(256) void emit_coords(
    const float* __restrict__ scd, const float* __restrict__ tcd,
    float* __restrict__ out)
{
  int i = blockIdx.x*256 + threadIdx.x;    // 0..49151
  out[i] = (i < NPTS*3) ? scd[i] : tcd[i - NPTS*3];
}

extern "C" void kernel_launch(void* const* d_in, const int* in_sizes, int n_in,
                              void* d_out, int out_size, void* d_ws, size_t ws_size,
                              hipStream_t stream)
{
  (void)in_sizes; (void)n_in; (void)out_size; (void)ws_size;
  const float* src   = (const float*)d_in[0];
  const float* tgt   = (const float*)d_in[1];
  const float* scd   = (const float*)d_in[2];
  const float* tcd   = (const float*)d_in[3];
  const float* W_in  = (const float*)d_in[4];
  const float* b_in  = (const float*)d_in[5];
  const float* kpts  = (const float*)d_in[6];
  const float* W_kp  = (const float*)d_in[7];
  const float* W_out = (const float*)d_in[8];
  const float* b_out = (const float*)d_in[9];
  const float* gamma = (const float*)d_in[10];
  const float* beta  = (const float*)d_in[11];

  // ---- workspace (peak ~9.3 MB) ----
  char* ws = (char*)d_ws;
  float*          h     = (float*)ws;                    // 0..4MB  [2][8192][64]
  float*          h2    = (float*)(ws + (4u<<20));       // 4..8MB (written by kpconv, after slots die)
  unsigned short* slots = (unsigned short*)(ws + (4u<<20)); // 4..8MB [16384][128] u16
  short*          fidx  = (short*)(ws + (8u<<20));       // 8..9MB [16384][32] i16
  unsigned int*   cnt   = (unsigned int*)(ws + (9u<<20));          // 64 KB
  float*          stats = (float*)(ws + (9u<<20) + (256u<<10));    // 4 KB

  float* yout = (float*)d_out;

  zero_u32<<<64, 256, 0, stream>>>(cnt, 2*NPTS);
  zero_u32<<<4, 256, 0, stream>>>((unsigned int*)stats, 1024);
  knn_gather<<<512, 128, 0, stream>>>(scd, tcd, cnt, slots);
  knn_select<<<256, 64, 0, stream>>>(scd, tcd, cnt, slots, fidx);
  conv_in_naive<<<4096, 256, 0, stream>>>(src, tgt, W_in, b_in, h);
  kpconv_fused<<<16384, 64, 0, stream>>>(scd, tcd, kpts, fidx, h, W_kp, h2);
  conv_out_naive<<<16384, 256, 0, stream>>>(h2, W_out, b_out, yout);
  bn_stats_k<<<64, 256, 0, stream>>>(yout, stats);
  bn_apply_k<<<16384, 256, 0, stream>>>(yout, stats, gamma, beta);
  emit_coords<<<192, 256, 0, stream>>>(scd, tcd, yout + (size_t)2*NPTS*OUTC);
}

// Round 10
// 769.268 us; speedup vs baseline: 4.0343x; 1.1785x over previous
//
#include <hip/hip_runtime.h>
#include <stdint.h>

#define NPTS 8192
#define KNN 32
#define KPN 15
#define SCC 64
#define OUTC 256
#define R2F 0.0144f              /* radius^2: the reference's in_range mask */
#define INV_EXT (1.0f/0.096f)
#define QPB 16                   /* queries per knn block */
#define PARTS 4
#define PCAP 48                  /* per-part survivor cap: lambda~14.8, P(>48)~7e-11 */
#define NT 4                     /* points per kpconv block */

// ---- generic zero -----------------------------------------------------------
__global__ void zero_u32(unsigned int* __restrict__ p, int n) {
  int i = blockIdx.x*256 + threadIdx.x;
  if (i < n) p[i] = 0u;
}

// ---- conv_in: one thread per (cloud,n,c); h[cloud][n][c] f32 -----------------
__global__ __launch_bounds__(256) void conv_in_naive(
    const float* __restrict__ src, const float* __restrict__ tgt,
    const float* __restrict__ W, const float* __restrict__ b,
    float* __restrict__ h)
{
  size_t e = (size_t)blockIdx.x*256 + threadIdx.x;   // < 2*8192*64 = 2^20
  int c = (int)(e & 63);
  int n = (int)((e >> 6) & 8191);
  int cloud = (int)(e >> 19);
  const float* x = cloud ? tgt : src;
  float acc = b[c];
  const float* xr = x + (size_t)n*256;
  for (int k = 0; k < 256; ++k)
    acc = fmaf(xr[k], W[(size_t)k*64 + c], acc);
  h[e] = acc;
}

// ---- fused kNN: no global atomics, all lists in LDS --------------------------
// Block: 64 threads = 16 queries x 4 parts. Part p scans candidate indices
// {chunk*1024 + p*256 + j} over 8 chunks (disjoint cover of all 8192).
// Survivors (d2 <= R2F) append to private LDS sub-lists (register count ->
// no atomic, no vmcnt stall). Then lane part==0 insert-evicts top-32 by
// key=(f32bits(d2)<<32)|idx — same key & set as the R9-proven selector.
__global__ __launch_bounds__(64) void knn_fused(
    const float* __restrict__ cA, const float* __restrict__ cB,
    short* __restrict__ fidx)
{
  __shared__ float4 cand[1024];                     // 16 KB (reused as lst)
  __shared__ float d2l[QPB][PARTS][PCAP+1];         // ~12.3 KB (pad: 2-way banks)
  __shared__ unsigned short idxl[QPB][PARTS][PCAP+1]; // ~6.1 KB
  __shared__ unsigned int ucnt[QPB][PARTS];         // 256 B
  int b = blockIdx.x;               // 1024: cloud(1)|qgroup(9)
  int cloud = b >> 9;
  int qg = b & 511;
  const float* coords = cloud ? cB : cA;
  int t = threadIdx.x;
  int ql = t >> 2, part = t & 3;
  int q = qg*QPB + ql;
  float qx = coords[(size_t)q*3];
  float qy = coords[(size_t)q*3+1];
  float qz = coords[(size_t)q*3+2];
  int pc = 0;
  for (int chunk = 0; chunk < 8; ++chunk) {
    __syncthreads();
    int base = chunk*1024;
    for (int i = t; i < 1024; i += 64) {
      size_t j = base + i;
      cand[i] = make_float4(coords[j*3], coords[j*3+1], coords[j*3+2], 0.f);
    }
    __syncthreads();
    int lo = part*256;
    #pragma unroll 4
    for (int jj = 0; jj < 256; ++jj) {
      int i = lo + jj;
      float4 c = cand[i];
      float dx = qx - c.x, dy = qy - c.y, dz = qz - c.z;
      float d2 = fmaf(dx, dx, fmaf(dy, dy, dz*dz));
      if (d2 <= R2F && pc < PCAP) {
        d2l[ql][part][pc] = d2;
        idxl[ql][part][pc] = (unsigned short)(base + i);
        ++pc;
      }
    }
  }
  ucnt[ql][part] = (unsigned int)pc;
  __syncthreads();
  if (part == 0) {
    unsigned long long* mylst = ((unsigned long long*)cand) + ql*33; // pad 33
    #pragma unroll
    for (int s = 0; s < KNN; ++s) mylst[s] = ~0ULL;
    unsigned long long curmax = ~0ULL;
    int maxslot = 0;
    for (int pp = 0; pp < PARTS; ++pp) {
      int C = (int)ucnt[ql][pp];
      for (int j = 0; j < C; ++j) {
        float d2 = d2l[ql][pp][j];
        unsigned int ci = idxl[ql][pp][j];
        unsigned long long key =
            ((unsigned long long)__float_as_uint(d2) << 32) | ci;
        if (key < curmax) {
          mylst[maxslot] = key;
          unsigned long long m = mylst[0]; int ms2 = 0;
          #pragma unroll
          for (int s = 1; s < KNN; ++s) {
            unsigned long long v = mylst[s];
            if (v > m) { m = v; ms2 = s; }
          }
          curmax = m; maxslot = ms2;
        }
      }
    }
    size_t g = (size_t)cloud*NPTS + q;
    #pragma unroll
    for (int s = 0; s < KNN; ++s)
      fidx[g*KNN + s] = (short)(mylst[s] & 0xffffu);  // 0xffff -> -1 sentinel
  }
}

// ---- fused KPConv, 4 points/block, W_kp staged via LDS -----------------------
// h2[n][d] = sum_{p,c} (sum_k infl[k][p] * h[nb_k][c]) * W_kp[p][c][d]
__global__ __launch_bounds__(256) void kpconv_fused(
    const float* __restrict__ cA, const float* __restrict__ cB,
    const float* __restrict__ kpts, const short* __restrict__ fidx,
    const float* __restrict__ h, const float* __restrict__ Wkp,
    float* __restrict__ h2)
{
  __shared__ float wkp_s[96*64];        // 24 KB chunk of W_kp rows
  __shared__ float w_s[NT][KNN][KPN];   // 7.5 KB
  __shared__ float agg_s[NT][KPN*SCC];  // 15 KB
  __shared__ int   idx_s[NT][KNN];
  int t = threadIdx.x;
  int w = t >> 6, lane = t & 63;
  int gq = blockIdx.x*NT + w;           // 0..16383 = cloud*NPTS + n
  int cloud = gq >> 13, n = gq & 8191;
  const float* coords = cloud ? cB : cA;
  if (lane < KNN) idx_s[w][lane] = fidx[(size_t)gq*KNN + lane];
  __syncthreads();
  float qx = coords[(size_t)n*3];
  float qy = coords[(size_t)n*3+1];
  float qz = coords[(size_t)n*3+2];
  for (int e = lane; e < KNN*KPN; e += 64) {
    int k = e / KPN, p = e % KPN;
    int idx = idx_s[w][k];
    float wv = 0.f;
    if (idx >= 0) {
      float rx = coords[(size_t)idx*3]   - qx;
      float ry = coords[(size_t)idx*3+1] - qy;
      float rz = coords[(size_t)idx*3+2] - qz;
      float dx = rx - kpts[0*3+0 + (size_t)p*3];
      float dy = ry - kpts[(size_t)p*3+1];
      float dz = rz - kpts[(size_t)p*3+2];
      float d = sqrtf(fmaf(dx, dx, fmaf(dy, dy, dz*dz)));
      wv = fmaxf(1.0f - d*INV_EXT, 0.0f);
    }
    w_s[w][k][p] = wv;
  }
  __syncthreads();
  // per-wave: agg[p][c] for c = lane
  float acc[KPN];
  #pragma unroll
  for (int p = 0; p < KPN; ++p) acc[p] = 0.f;
  for (int k = 0; k < KNN; ++k) {
    int idx = idx_s[w][k];                // wave-uniform
    if (idx < 0) continue;
    float f = h[((size_t)(cloud*NPTS + idx))*SCC + lane];
    #pragma unroll
    for (int p = 0; p < KPN; ++p) acc[p] = fmaf(w_s[w][k][p], f, acc[p]);
  }
  #pragma unroll
  for (int p = 0; p < KPN; ++p) agg_s[w][p*SCC + lane] = acc[p];
  // contract in 96-row chunks of W_kp staged cooperatively (10 chunks x 96 = 960)
  float out = 0.f;
  for (int c0 = 0; c0 < KPN*SCC; c0 += 96) {
    __syncthreads();
    const float4* gsrc = (const float4*)(Wkp + (size_t)c0*64);
    float4* ldst = (float4*)wkp_s;
    for (int i = t; i < 96*64/4; i += 256) ldst[i] = gsrc[i];
    __syncthreads();
    #pragma unroll 4
    for (int j = 0; j < 96; ++j)
      out = fmaf(agg_s[w][c0 + j], wkp_s[j*64 + lane], out);
  }
  h2[(size_t)gq*SCC + lane] = out;
}

// ---- conv_out: one thread per (cloud,n,d), f32 out ---------------------------
__global__ __launch_bounds__(256) void conv_out_naive(
    const float* __restrict__ h2, const float* __restrict__ W,
    const float* __restrict__ b, float* __restrict__ y)
{
  size_t e = (size_t)blockIdx.x*256 + threadIdx.x;   // < 2*8192*256 = 2^22
  int d = (int)(e & 255);
  size_t nrow = e >> 8;            // cloud*8192 + n
  float acc = b[d];
  const float* hr = h2 + nrow*SCC;
  for (int c = 0; c < SCC; ++c)
    acc = fmaf(hr[c], W[(size_t)c*256 + d], acc);
  y[e] = acc;
}

// ---- BN ----------------------------------------------------------------------
__global__ __launch_bounds__(256) void bn_stats_k(
    const float* __restrict__ y, float* __restrict__ stats)
{
  int b = blockIdx.x;          // 64 blocks
  int cloud = b >> 5, rb = b & 31;
  int c = threadIdx.x;
  size_t base = ((size_t)(cloud*NPTS + rb*256))*OUTC + c;
  float s = 0.f, s2 = 0.f;
  for (int r = 0; r < 256; ++r) {
    float v = y[base + (size_t)r*OUTC];
    s += v; s2 = fmaf(v, v, s2);
  }
  atomicAdd(&stats[cloud*512 + c], s);
  atomicAdd(&stats[cloud*512 + 256 + c], s2);
}

__global__ __launch_bounds__(256) void bn_apply_k(
    float* __restrict__ y, const float* __restrict__ stats,
    const float* __restrict__ gamma, const float* __restrict__ beta)
{
  size_t e = (size_t)blockIdx.x*256 + threadIdx.x;
  int c = (int)(e & 255);
  int cloud = (int)(e >> 21);
  float s  = stats[cloud*512 + c];
  float s2 = stats[cloud*512 + 256 + c];
  float mu  = s * (1.0f/NPTS);
  float var = fmaxf(s2 * (1.0f/NPTS) - mu*mu, 0.f);
  float sc = gamma[c] * rsqrtf(var + 1e-5f);
  float sh = beta[c] - mu*sc;
  float v = fmaf(y[e], sc, sh);
  v = v > 0.f ? v : 0.1f*v;
  y[e] = v;
}

// ---- coords tail of output (f32) --------------------------------------------
__global__ __launch_bounds__(256) void emit_coords(
    const float* __restrict__ scd, const float* __restrict__ tcd,
    float* __restrict__ out)
{
  int i = blockIdx.x*256 + threadIdx.x;    // 0..49151
  out[i] = (i < NPTS*3) ? scd[i] : tcd[i - NPTS*3];
}

extern "C" void kernel_launch(void* const* d_in, const int* in_sizes, int n_in,
                              void* d_out, int out_size, void* d_ws, size_t ws_size,
                              hipStream_t stream)
{
  (void)in_sizes; (void)n_in; (void)out_size; (void)ws_size;
  const float* src   = (const float*)d_in[0];
  const float* tgt   = (const float*)d_in[1];
  const float* scd   = (const float*)d_in[2];
  const float* tcd   = (const float*)d_in[3];
  const float* W_in  = (const float*)d_in[4];
  const float* b_in  = (const float*)d_in[5];
  const float* kpts  = (const float*)d_in[6];
  const float* W_kp  = (const float*)d_in[7];
  const float* W_out = (const float*)d_in[8];
  const float* b_out = (const float*)d_in[9];
  const float* gamma = (const float*)d_in[10];
  const float* beta  = (const float*)d_in[11];

  // ---- workspace (peak ~9.0 MB) ----
  char* ws = (char*)d_ws;
  float* h     = (float*)ws;                        // 0..4 MB  [2][8192][64]
  float* h2    = (float*)(ws + (4u<<20));           // 4..8 MB
  short* fidx  = (short*)(ws + (8u<<20));           // 8..9 MB [16384][32] i16
  float* stats = (float*)(ws + (9u<<20));           // 4 KB

  float* yout = (float*)d_out;

  zero_u32<<<4, 256, 0, stream>>>((unsigned int*)stats, 1024);
  knn_fused<<<1024, 64, 0, stream>>>(scd, tcd, fidx);
  conv_in_naive<<<4096, 256, 0, stream>>>(src, tgt, W_in, b_in, h);
  kpconv_fused<<<4096, 256, 0, stream>>>(scd, tcd, kpts, fidx, h, W_kp, h2);
  conv_out_naive<<<16384, 256, 0, stream>>>(h2, W_out, b_out, yout);
  bn_stats_k<<<64, 256, 0, stream>>>(yout, stats);
  bn_apply_k<<<16384, 256, 0, stream>>>(yout, stats, gamma, beta);
  emit_coords<<<192, 256, 0, stream>>>(scd, tcd, yout + (size_t)2*NPTS*OUTC);
}

// Round 11
// 516.587 us; speedup vs baseline: 6.0077x; 1.4891x over previous
//
#include <hip/hip_runtime.h>
#include <stdint.h>

#define NPTS 8192
#define KNN 32
#define KPN 15
#define SCC 64
#define OUTC 256
#define R2F 0.0144f              /* radius^2: the reference's in_range mask */
#define INV_EXT (1.0f/0.096f)
#define SCAP 128                 /* per-query survivor cap; P(Poisson(<=59)>128)<1e-14 */
#define NT 4                     /* points per kpconv block */

// ---- generic zero -----------------------------------------------------------
__global__ void zero_u32(unsigned int* __restrict__ p, int n) {
  int i = blockIdx.x*256 + threadIdx.x;
  if (i < n) p[i] = 0u;
}

// ---- conv_in: one thread per (cloud,n,c); h[cloud][n][c] f32 -----------------
__global__ __launch_bounds__(256) void conv_in_naive(
    const float* __restrict__ src, const float* __restrict__ tgt,
    const float* __restrict__ W, const float* __restrict__ b,
    float* __restrict__ h)
{
  size_t e = (size_t)blockIdx.x*256 + threadIdx.x;   // < 2*8192*64 = 2^20
  int c = (int)(e & 63);
  int n = (int)((e >> 6) & 8191);
  int cloud = (int)(e >> 19);
  const float* x = cloud ? tgt : src;
  float acc = b[c];
  const float* xr = x + (size_t)n*256;
  for (int k = 0; k < 256; ++k)
    acc = fmaf(xr[k], W[(size_t)k*64 + c], acc);
  h[e] = acc;
}

// ---- kNN: one wave per query, LDS-atomic gather + wave rank-select -----------
// Lane l of query-wave scans candidates {chunk*2048 + l + 64*j}. cbuf is flat
// f32 (stride-3 lane access: gcd(3,32)=1 -> 2 lanes/bank = conflict-free).
// Survivors appended to per-query LDS list via LDS atomic (no vmcnt).
// Select: rank of each survivor key among all -> rank<32 writes fidx[rank].
// Keys (f32bits(d2)<<32)|idx: identical set & order as the R9/R10 selector.
__global__ __launch_bounds__(256) void knn_par(
    const float* __restrict__ cA, const float* __restrict__ cB,
    short* __restrict__ fidx)
{
  __shared__ float cbuf[2048*3];                  // 24 KB
  __shared__ unsigned long long surv[NT][SCAP];   // 4 KB
  __shared__ unsigned int scnt[NT];
  int b = blockIdx.x;                // 4096 blocks: cloud(1)|qg(11)
  int cloud = b >> 11;
  int qg = b & 2047;
  const float* coords = cloud ? cB : cA;
  int t = threadIdx.x;
  int w = t >> 6, lane = t & 63;
  int q = qg*NT + w;
  float qx = coords[(size_t)q*3];
  float qy = coords[(size_t)q*3+1];
  float qz = coords[(size_t)q*3+2];
  if (t < NT) scnt[t] = 0u;
  for (int chunk = 0; chunk < 4; ++chunk) {
    __syncthreads();
    int base = chunk*2048;
    const float* gsrc = coords + (size_t)base*3;
    for (int i = t; i < 2048*3; i += 256) cbuf[i] = gsrc[i];
    __syncthreads();
    #pragma unroll 8
    for (int j = 0; j < 32; ++j) {
      int i = lane + 64*j;
      float dx = qx - cbuf[i*3];
      float dy = qy - cbuf[i*3+1];
      float dz = qz - cbuf[i*3+2];
      float d2 = fmaf(dx, dx, fmaf(dy, dy, dz*dz));
      if (d2 <= R2F) {
        unsigned int pos = atomicAdd(&scnt[w], 1u);
        if (pos < SCAP)
          surv[w][pos] = ((unsigned long long)__float_as_uint(d2) << 32)
                         | (unsigned int)(base + i);
      }
    }
  }
  __syncthreads();
  int C = (int)scnt[w]; if (C > SCAP) C = SCAP;
  unsigned long long k0 = (lane      < C) ? surv[w][lane]      : ~0ULL;
  unsigned long long k1 = (lane + 64 < C) ? surv[w][lane + 64] : ~0ULL;
  int r0 = 0, r1 = 0;
  for (int j = 0; j < C; ++j) {
    unsigned long long kj = surv[w][j];       // same addr all lanes: broadcast
    r0 += (kj < k0);
    r1 += (kj < k1);
  }
  size_t g = (size_t)cloud*NPTS + q;
  if (k0 != ~0ULL && r0 < KNN) fidx[g*KNN + r0] = (short)(k0 & 0xffffu);
  if (k1 != ~0ULL && r1 < KNN) fidx[g*KNN + r1] = (short)(k1 & 0xffffu);
  if (lane >= C && lane < KNN) fidx[g*KNN + lane] = (short)-1;  // sentinel fill
}

// ---- fused KPConv, 4 points/block, W_kp staged via LDS -----------------------
// h2[n][d] = sum_{p,c} (sum_k infl[k][p] * h[nb_k][c]) * W_kp[p][c][d]
__global__ __launch_bounds__(256) void kpconv_fused(
    const float* __restrict__ cA, const float* __restrict__ cB,
    const float* __restrict__ kpts, const short* __restrict__ fidx,
    const float* __restrict__ h, const float* __restrict__ Wkp,
    float* __restrict__ h2)
{
  __shared__ float wkp_s[96*64];        // 24 KB chunk of W_kp rows
  __shared__ float w_s[NT][KNN][KPN];   // 7.5 KB
  __shared__ float agg_s[NT][KPN*SCC];  // 15 KB
  __shared__ int   idx_s[NT][KNN];
  int t = threadIdx.x;
  int w = t >> 6, lane = t & 63;
  int gq = blockIdx.x*NT + w;           // 0..16383 = cloud*NPTS + n
  int cloud = gq >> 13, n = gq & 8191;
  const float* coords = cloud ? cB : cA;
  if (lane < KNN) idx_s[w][lane] = fidx[(size_t)gq*KNN + lane];
  __syncthreads();
  float qx = coords[(size_t)n*3];
  float qy = coords[(size_t)n*3+1];
  float qz = coords[(size_t)n*3+2];
  for (int e = lane; e < KNN*KPN; e += 64) {
    int k = e / KPN, p = e % KPN;
    int idx = idx_s[w][k];
    float wv = 0.f;
    if (idx >= 0) {
      float rx = coords[(size_t)idx*3]   - qx;
      float ry = coords[(size_t)idx*3+1] - qy;
      float rz = coords[(size_t)idx*3+2] - qz;
      float dx = rx - kpts[(size_t)p*3];
      float dy = ry - kpts[(size_t)p*3+1];
      float dz = rz - kpts[(size_t)p*3+2];
      float d = sqrtf(fmaf(dx, dx, fmaf(dy, dy, dz*dz)));
      wv = fmaxf(1.0f - d*INV_EXT, 0.0f);
    }
    w_s[w][k][p] = wv;
  }
  __syncthreads();
  // per-wave: agg[p][c] for c = lane
  float acc[KPN];
  #pragma unroll
  for (int p = 0; p < KPN; ++p) acc[p] = 0.f;
  for (int k = 0; k < KNN; ++k) {
    int idx = idx_s[w][k];                // wave-uniform
    if (idx < 0) continue;
    float f = h[((size_t)(cloud*NPTS + idx))*SCC + lane];
    #pragma unroll
    for (int p = 0; p < KPN; ++p) acc[p] = fmaf(w_s[w][k][p], f, acc[p]);
  }
  #pragma unroll
  for (int p = 0; p < KPN; ++p) agg_s[w][p*SCC + lane] = acc[p];
  // contract in 96-row chunks of W_kp staged cooperatively (10 chunks x 96 = 960)
  float out = 0.f;
  for (int c0 = 0; c0 < KPN*SCC; c0 += 96) {
    __syncthreads();
    const float4* gsrc = (const float4*)(Wkp + (size_t)c0*64);
    float4* ldst = (float4*)wkp_s;
    for (int i = t; i < 96*64/4; i += 256) ldst[i] = gsrc[i];
    __syncthreads();
    #pragma unroll 4
    for (int j = 0; j < 96; ++j)
      out = fmaf(agg_s[w][c0 + j], wkp_s[j*64 + lane], out);
  }
  h2[(size_t)gq*SCC + lane] = out;
}

// ---- conv_out: one thread per (cloud,n,d), f32 out ---------------------------
__global__ __launch_bounds__(256) void conv_out_naive(
    const float* __restrict__ h2, const float* __restrict__ W,
    const float* __restrict__ b, float* __restrict__ y)
{
  size_t e = (size_t)blockIdx.x*256 + threadIdx.x;   // < 2*8192*256 = 2^22
  int d = (int)(e & 255);
  size_t nrow = e >> 8;            // cloud*8192 + n
  float acc = b[d];
  const float* hr = h2 + nrow*SCC;
  for (int c = 0; c < SCC; ++c)
    acc = fmaf(hr[c], W[(size_t)c*256 + d], acc);
  y[e] = acc;
}

// ---- BN ----------------------------------------------------------------------
__global__ __launch_bounds__(256) void bn_stats_k(
    const float* __restrict__ y, float* __restrict__ stats)
{
  int b = blockIdx.x;          // 64 blocks
  int cloud = b >> 5, rb = b & 31;
  int c = threadIdx.x;
  size_t base = ((size_t)(cloud*NPTS + rb*256))*OUTC + c;
  float s = 0.f, s2 = 0.f;
  for (int r = 0; r < 256; ++r) {
    float v = y[base + (size_t)r*OUTC];
    s += v; s2 = fmaf(v, v, s2);
  }
  atomicAdd(&stats[cloud*512 + c], s);
  atomicAdd(&stats[cloud*512 + 256 + c], s2);
}

__global__ __launch_bounds__(256) void bn_apply_k(
    float* __restrict__ y, const float* __restrict__ stats,
    const float* __restrict__ gamma, const float* __restrict__ beta)
{
  size_t e = (size_t)blockIdx.x*256 + threadIdx.x;
  int c = (int)(e & 255);
  int cloud = (int)(e >> 21);
  float s  = stats[cloud*512 + c];
  float s2 = stats[cloud*512 + 256 + c];
  float mu  = s * (1.0f/NPTS);
  float var = fmaxf(s2 * (1.0f/NPTS) - mu*mu, 0.f);
  float sc = gamma[c] * rsqrtf(var + 1e-5f);
  float sh = beta[c] - mu*sc;
  float v = fmaf(y[e], sc, sh);
  v = v > 0.f ? v : 0.1f*v;
  y[e] = v;
}

// ---- coords tail of output (f32) --------------------------------------------
__global__ __launch_bounds__(256) void emit_coords(
    const float* __restrict__ scd, const float* __restrict__ tcd,
    float* __restrict__ out)
{
  int i = blockIdx.x*256 + threadIdx.x;    // 0..49151
  out[i] = (i < NPTS*3) ? scd[i] : tcd[i - NPTS*3];
}

extern "C" void kernel_launch(void* const* d_in, const int* in_sizes, int n_in,
                              void* d_out, int out_size, void* d_ws, size_t ws_size,
                              hipStream_t stream)
{
  (void)in_sizes; (void)n_in; (void)out_size; (void)ws_size;
  const float* src   = (const float*)d_in[0];
  const float* tgt   = (const float*)d_in[1];
  const float* scd   = (const float*)d_in[2];
  const float* tcd   = (const float*)d_in[3];
  const float* W_in  = (const float*)d_in[4];
  const float* b_in  = (const float*)d_in[5];
  const float* kpts  = (const float*)d_in[6];
  const float* W_kp  = (const float*)d_in[7];
  const float* W_out = (const float*)d_in[8];
  const float* b_out = (const float*)d_in[9];
  const float* gamma = (const float*)d_in[10];
  const float* beta  = (const float*)d_in[11];

  // ---- workspace (peak ~9.0 MB) ----
  char* ws = (char*)d_ws;
  float* h     = (float*)ws;                        // 0..4 MB  [2][8192][64]
  float* h2    = (float*)(ws + (4u<<20));           // 4..8 MB
  short* fidx  = (short*)(ws + (8u<<20));           // 8..9 MB [16384][32] i16
  float* stats = (float*)(ws + (9u<<20));           // 4 KB

  float* yout = (float*)d_out;

  zero_u32<<<4, 256, 0, stream>>>((unsigned int*)stats, 1024);
  knn_par<<<4096, 256, 0, stream>>>(scd, tcd, fidx);
  conv_in_naive<<<4096, 256, 0, stream>>>(src, tgt, W_in, b_in, h);
  kpconv_fused<<<4096, 256, 0, stream>>>(scd, tcd, kpts, fidx, h, W_kp, h2);
  conv_out_naive<<<16384, 256, 0, stream>>>(h2, W_out, b_out, yout);
  bn_stats_k<<<64, 256, 0, stream>>>(yout, stats);
  bn_apply_k<<<16384, 256, 0, stream>>>(yout, stats, gamma, beta);
  emit_coords<<<192, 256, 0, stream>>>(scd, tcd, yout + (size_t)2*NPTS*OUTC);
}

// Round 12
// 433.144 us; speedup vs baseline: 7.1650x; 1.1926x over previous
//
#include <hip/hip_runtime.h>
#include <stdint.h>

#define NPTS 8192
#define KNN 32
#define KPN 15
#define SCC 64
#define OUTC 256
#define R2F 0.0144f              /* radius^2: the reference's in_range mask */
#define INV_EXT (1.0f/0.096f)
#define SCAP 128                 /* per-query survivor cap */
#define NT 4                     /* points per kpconv block */

// ---- generic zero -----------------------------------------------------------
__global__ void zero_u32(unsigned int* __restrict__ p, int n) {
  int i = blockIdx.x*256 + threadIdx.x;
  if (i < n) p[i] = 0u;
}

// ---- conv_in: one thread per (cloud,n,c); h[cloud][n][c] f32 -----------------
__global__ __launch_bounds__(256) void conv_in_naive(
    const float* __restrict__ src, const float* __restrict__ tgt,
    const float* __restrict__ W, const float* __restrict__ b,
    float* __restrict__ h)
{
  size_t e = (size_t)blockIdx.x*256 + threadIdx.x;   // < 2*8192*64 = 2^20
  int c = (int)(e & 63);
  int n = (int)((e >> 6) & 8191);
  int cloud = (int)(e >> 19);
  const float* x = cloud ? tgt : src;
  float acc = b[c];
  const float* xr = x + (size_t)n*256;
  for (int k = 0; k < 256; ++k)
    acc = fmaf(xr[k], W[(size_t)k*64 + c], acc);
  h[e] = acc;
}

// ---- kNN: one wave per query, LDS-atomic gather + wave rank-select -----------
__global__ __launch_bounds__(256) void knn_par(
    const float* __restrict__ cA, const float* __restrict__ cB,
    short* __restrict__ fidx)
{
  __shared__ float cbuf[2048*3];                  // 24 KB
  __shared__ unsigned long long surv[NT][SCAP];   // 4 KB
  __shared__ unsigned int scnt[NT];
  int b = blockIdx.x;                // 4096 blocks: cloud(1)|qg(11)
  int cloud = b >> 11;
  int qg = b & 2047;
  const float* coords = cloud ? cB : cA;
  int t = threadIdx.x;
  int w = t >> 6, lane = t & 63;
  int q = qg*NT + w;
  float qx = coords[(size_t)q*3];
  float qy = coords[(size_t)q*3+1];
  float qz = coords[(size_t)q*3+2];
  if (t < NT) scnt[t] = 0u;
  for (int chunk = 0; chunk < 4; ++chunk) {
    __syncthreads();
    int base = chunk*2048;
    const float* gsrc = coords + (size_t)base*3;
    for (int i = t; i < 2048*3; i += 256) cbuf[i] = gsrc[i];
    __syncthreads();
    #pragma unroll 8
    for (int j = 0; j < 32; ++j) {
      int i = lane + 64*j;
      float dx = qx - cbuf[i*3];
      float dy = qy - cbuf[i*3+1];
      float dz = qz - cbuf[i*3+2];
      float d2 = fmaf(dx, dx, fmaf(dy, dy, dz*dz));
      if (d2 <= R2F) {
        unsigned int pos = atomicAdd(&scnt[w], 1u);
        if (pos < SCAP)
          surv[w][pos] = ((unsigned long long)__float_as_uint(d2) << 32)
                         | (unsigned int)(base + i);
      }
    }
  }
  __syncthreads();
  int C = (int)scnt[w]; if (C > SCAP) C = SCAP;
  unsigned long long k0 = (lane      < C) ? surv[w][lane]      : ~0ULL;
  unsigned long long k1 = (lane + 64 < C) ? surv[w][lane + 64] : ~0ULL;
  int r0 = 0, r1 = 0;
  for (int j = 0; j < C; ++j) {
    unsigned long long kj = surv[w][j];       // same addr all lanes: broadcast
    r0 += (kj < k0);
    r1 += (kj < k1);
  }
  size_t g = (size_t)cloud*NPTS + q;
  if (k0 != ~0ULL && r0 < KNN) fidx[g*KNN + r0] = (short)(k0 & 0xffffu);
  if (k1 != ~0ULL && r1 < KNN) fidx[g*KNN + r1] = (short)(k1 & 0xffffu);
  if (lane >= C && lane < KNN) fidx[g*KNN + lane] = (short)-1;  // sentinel fill
}

// ---- fused KPConv, 4 points/block ---------------------------------------------
// Phase A (per wave = per point, as R11-proven): agg[pt][j=p*64+c] in LDS.
// Phase B (new): contraction h2 = agg @ Wkp with W_kp chunk shared by ALL 4
// points: wave w covers j-slice [c0+w*16, +16) for all 4 points; lane jg=l>>4
// handles rows jg*4+g, dims (l&15)*4.. (dense b128 wkp reads, b128 broadcast
// agg reads). Partials reduced via shfl_xor(16,32) then across waves in LDS.
__global__ __launch_bounds__(256) void kpconv_fused(
    const float* __restrict__ cA, const float* __restrict__ cB,
    const float* __restrict__ kpts, const short* __restrict__ fidx,
    const float* __restrict__ h, const float* __restrict__ Wkp,
    float* __restrict__ h2)
{
  __shared__ float wkp_s[64*64];        // 16 KB: 64-row chunk of W_kp
  __shared__ float w_s[NT][KNN][16];    // 8 KB (p padded to 16, [15]=0)
  __shared__ float agg_s[NT][KPN*SCC];  // 15 KB, j = p*64+c
  __shared__ float red_s[NT][NT*SCC];   // 4 KB  [wave][pt*64+d]
  __shared__ int   idx_s[NT][KNN];
  int t = threadIdx.x;
  int w = t >> 6, lane = t & 63;
  int gq = blockIdx.x*NT + w;           // 0..16383 = cloud*NPTS + n
  int cloud = gq >> 13, n = gq & 8191;
  const float* coords = cloud ? cB : cA;
  if (lane < KNN) idx_s[w][lane] = fidx[(size_t)gq*KNN + lane];
  __syncthreads();
  float qx = coords[(size_t)n*3];
  float qy = coords[(size_t)n*3+1];
  float qz = coords[(size_t)n*3+2];
  for (int e = lane; e < KNN*16; e += 64) {
    int k = e >> 4, p = e & 15;
    int idx = idx_s[w][k];
    float wv = 0.f;
    if (idx >= 0 && p < KPN) {
      float rx = coords[(size_t)idx*3]   - qx;
      float ry = coords[(size_t)idx*3+1] - qy;
      float rz = coords[(size_t)idx*3+2] - qz;
      float dx = rx - kpts[(size_t)p*3];
      float dy = ry - kpts[(size_t)p*3+1];
      float dz = rz - kpts[(size_t)p*3+2];
      float d = sqrtf(fmaf(dx, dx, fmaf(dy, dy, dz*dz)));
      wv = fmaxf(1.0f - d*INV_EXT, 0.0f);
    }
    w_s[w][k][p] = wv;
  }
  __syncthreads();
  // Phase A: agg[p][c] for c = lane (acc[15] is a dummy fed by w==0)
  float acc[16];
  #pragma unroll
  for (int p = 0; p < 16; ++p) acc[p] = 0.f;
  for (int k = 0; k < KNN; ++k) {
    int idx = idx_s[w][k];                // wave-uniform
    if (idx < 0) continue;
    float f = h[((size_t)(cloud*NPTS + idx))*SCC + lane];
    const float4* wr = (const float4*)&w_s[w][k][0];
    #pragma unroll
    for (int g = 0; g < 4; ++g) {
      float4 w4 = wr[g];
      acc[g*4+0] = fmaf(w4.x, f, acc[g*4+0]);
      acc[g*4+1] = fmaf(w4.y, f, acc[g*4+1]);
      acc[g*4+2] = fmaf(w4.z, f, acc[g*4+2]);
      acc[g*4+3] = fmaf(w4.w, f, acc[g*4+3]);
    }
  }
  #pragma unroll
  for (int p = 0; p < KPN; ++p) agg_s[w][p*SCC + lane] = acc[p];
  // Phase B: shared-W contraction
  int jg = lane >> 4;            // 0..3
  int dq = (lane & 15) * 4;      // dim group
  float4 acc4[NT];
  #pragma unroll
  for (int pt = 0; pt < NT; ++pt) acc4[pt] = make_float4(0.f,0.f,0.f,0.f);
  for (int c0 = 0; c0 < KPN*SCC; c0 += 64) {
    __syncthreads();
    {
      const float4* gsrc = (const float4*)(Wkp + (size_t)c0*64);
      float4* ldst = (float4*)wkp_s;
      ldst[t]       = gsrc[t];
      ldst[t + 256] = gsrc[t + 256];
      ldst[t + 512] = gsrc[t + 512];
      ldst[t + 768] = gsrc[t + 768];
    }
    __syncthreads();
    int jbase = w*16 + jg*4;     // local row base within chunk
    float4 wv[4];
    #pragma unroll
    for (int g = 0; g < 4; ++g)
      wv[g] = *(const float4*)&wkp_s[(jbase + g)*64 + dq];
    #pragma unroll
    for (int pt = 0; pt < NT; ++pt) {
      float4 av = *(const float4*)&agg_s[pt][c0 + jbase];
      float a[4] = {av.x, av.y, av.z, av.w};
      #pragma unroll
      for (int g = 0; g < 4; ++g) {
        acc4[pt].x = fmaf(a[g], wv[g].x, acc4[pt].x);
        acc4[pt].y = fmaf(a[g], wv[g].y, acc4[pt].y);
        acc4[pt].z = fmaf(a[g], wv[g].z, acc4[pt].z);
        acc4[pt].w = fmaf(a[g], wv[g].w, acc4[pt].w);
      }
    }
  }
  // reduce over jg lane-groups (bits 4,5 of lane)
  #pragma unroll
  for (int pt = 0; pt < NT; ++pt) {
    acc4[pt].x += __shfl_xor(acc4[pt].x, 16); acc4[pt].x += __shfl_xor(acc4[pt].x, 32);
    acc4[pt].y += __shfl_xor(acc4[pt].y, 16); acc4[pt].y += __shfl_xor(acc4[pt].y, 32);
    acc4[pt].z += __shfl_xor(acc4[pt].z, 16); acc4[pt].z += __shfl_xor(acc4[pt].z, 32);
    acc4[pt].w += __shfl_xor(acc4[pt].w, 16); acc4[pt].w += __shfl_xor(acc4[pt].w, 32);
  }
  __syncthreads();
  if (lane < 16) {
    #pragma unroll
    for (int pt = 0; pt < NT; ++pt)
      *(float4*)&red_s[w][pt*SCC + dq] = acc4[pt];
  }
  __syncthreads();
  {
    int pt = t >> 6, d = t & 63;     // one output element per thread
    float s = red_s[0][pt*SCC + d] + red_s[1][pt*SCC + d]
            + red_s[2][pt*SCC + d] + red_s[3][pt*SCC + d];
    h2[((size_t)blockIdx.x*NT + pt)*SCC + d] = s;
  }
}

// ---- conv_out: one thread per (cloud,n,d), f32 out ---------------------------
__global__ __launch_bounds__(256) void conv_out_naive(
    const float* __restrict__ h2, const float* __restrict__ W,
    const float* __restrict__ b, float* __restrict__ y)
{
  size_t e = (size_t)blockIdx.x*256 + threadIdx.x;   // < 2*8192*256 = 2^22
  int d = (int)(e & 255);
  size_t nrow = e >> 8;            // cloud*8192 + n
  float acc = b[d];
  const float* hr = h2 + nrow*SCC;
  for (int c = 0; c < SCC; ++c)
    acc = fmaf(hr[c], W[(size_t)c*256 + d], acc);
  y[e] = acc;
}

// ---- BN ----------------------------------------------------------------------
__global__ __launch_bounds__(256) void bn_stats_k(
    const float* __restrict__ y, float* __restrict__ stats)
{
  int b = blockIdx.x;          // 512 blocks: cloud(1)|rb(8), 32 rows each
  int cloud = b >> 8, rb = b & 255;
  int c = threadIdx.x;
  size_t base = ((size_t)(cloud*NPTS + rb*32))*OUTC + c;
  float s = 0.f, s2 = 0.f;
  for (int r = 0; r < 32; ++r) {
    float v = y[base + (size_t)r*OUTC];
    s += v; s2 = fmaf(v, v, s2);
  }
  atomicAdd(&stats[cloud*512 + c], s);
  atomicAdd(&stats[cloud*512 + 256 + c], s2);
}

__global__ __launch_bounds__(256) void bn_apply_k(
    float* __restrict__ y, const float* __restrict__ stats,
    const float* __restrict__ gamma, const float* __restrict__ beta)
{
  size_t e = (size_t)blockIdx.x*256 + threadIdx.x;
  int c = (int)(e & 255);
  int cloud = (int)(e >> 21);
  float s  = stats[cloud*512 + c];
  float s2 = stats[cloud*512 + 256 + c];
  float mu  = s * (1.0f/NPTS);
  float var = fmaxf(s2 * (1.0f/NPTS) - mu*mu, 0.f);
  float sc = gamma[c] * rsqrtf(var + 1e-5f);
  float sh = beta[c] - mu*sc;
  float v = fmaf(y[e], sc, sh);
  v = v > 0.f ? v : 0.1f*v;
  y[e] = v;
}

// ---- coords tail of output (f32) --------------------------------------------
__global__ __launch_bounds__(256) void emit_coords(
    const float* __restrict__ scd, const float* __restrict__ tcd,
    float* __restrict__ out)
{
  int i = blockIdx.x*256 + threadIdx.x;    // 0..49151
  out[i] = (i < NPTS*3) ? scd[i] : tcd[i - NPTS*3];
}

extern "C" void kernel_launch(void* const* d_in, const int* in_sizes, int n_in,
                              void* d_out, int out_size, void* d_ws, size_t ws_size,
                              hipStream_t stream)
{
  (void)in_sizes; (void)n_in; (void)out_size; (void)ws_size;
  const float* src   = (const float*)d_in[0];
  const float* tgt   = (const float*)d_in[1];
  const float* scd   = (const float*)d_in[2];
  const float* tcd   = (const float*)d_in[3];
  const float* W_in  = (const float*)d_in[4];
  const float* b_in  = (const float*)d_in[5];
  const float* kpts  = (const float*)d_in[6];
  const float* W_kp  = (const float*)d_in[7];
  const float* W_out = (const float*)d_in[8];
  const float* b_out = (const float*)d_in[9];
  const float* gamma = (const float*)d_in[10];
  const float* beta  = (const float*)d_in[11];

  // ---- workspace (peak ~9.0 MB) ----
  char* ws = (char*)d_ws;
  float* h     = (float*)ws;                        // 0..4 MB  [2][8192][64]
  float* h2    = (float*)(ws + (4u<<20));           // 4..8 MB
  short* fidx  = (short*)(ws + (8u<<20));           // 8..9 MB [16384][32] i16
  float* stats = (float*)(ws + (9u<<20));           // 4 KB

  float* yout = (float*)d_out;

  zero_u32<<<4, 256, 0, stream>>>((unsigned int*)stats, 1024);
  knn_par<<<4096, 256, 0, stream>>>(scd, tcd, fidx);
  conv_in_naive<<<4096, 256, 0, stream>>>(src, tgt, W_in, b_in, h);
  kpconv_fused<<<4096, 256, 0, stream>>>(scd, tcd, kpts, fidx, h, W_kp, h2);
  conv_out_naive<<<16384, 256, 0, stream>>>(h2, W_out, b_out, yout);
  bn_stats_k<<<512, 256, 0, stream>>>(yout, stats);
  bn_apply_k<<<16384, 256, 0, stream>>>(yout, stats, gamma, beta);
  emit_coords<<<192, 256, 0, stream>>>(scd, tcd, yout + (size_t)2*NPTS*OUTC);
}

// Round 13
// 407.097 us; speedup vs baseline: 7.6235x; 1.0640x over previous
//
#include <hip/hip_runtime.h>
#include <stdint.h>

#define NPTS 8192
#define KNN 32
#define KPN 15
#define SCC 64
#define OUTC 256
#define R2F 0.0144f              /* radius^2: the reference's in_range mask */
#define INV_EXT (1.0f/0.096f)
#define SCAP 128                 /* per-query survivor cap */
#define NT 4                     /* points per kpconv block */

// ---- conv_in: one thread per (cloud,n,c); h[cloud][n][c] f32 -----------------
__global__ __launch_bounds__(256) void conv_in_naive(
    const float* __restrict__ src, const float* __restrict__ tgt,
    const float* __restrict__ W, const float* __restrict__ b,
    float* __restrict__ h)
{
  size_t e = (size_t)blockIdx.x*256 + threadIdx.x;   // < 2*8192*64 = 2^20
  int c = (int)(e & 63);
  int n = (int)((e >> 6) & 8191);
  int cloud = (int)(e >> 19);
  const float* x = cloud ? tgt : src;
  float acc = b[c];
  const float* xr = x + (size_t)n*256;
  for (int k = 0; k < 256; ++k)
    acc = fmaf(xr[k], W[(size_t)k*64 + c], acc);
  h[e] = acc;
}

// ---- kNN: one wave per query, LDS-atomic gather + wave rank-select -----------
__global__ __launch_bounds__(256) void knn_par(
    const float* __restrict__ cA, const float* __restrict__ cB,
    short* __restrict__ fidx)
{
  __shared__ float cbuf[2048*3];                  // 24 KB
  __shared__ unsigned long long surv[NT][SCAP];   // 4 KB
  __shared__ unsigned int scnt[NT];
  int b = blockIdx.x;                // 4096 blocks: cloud(1)|qg(11)
  int cloud = b >> 11;
  int qg = b & 2047;
  const float* coords = cloud ? cB : cA;
  int t = threadIdx.x;
  int w = t >> 6, lane = t & 63;
  int q = qg*NT + w;
  float qx = coords[(size_t)q*3];
  float qy = coords[(size_t)q*3+1];
  float qz = coords[(size_t)q*3+2];
  if (t < NT) scnt[t] = 0u;
  for (int chunk = 0; chunk < 4; ++chunk) {
    __syncthreads();
    int base = chunk*2048;
    const float* gsrc = coords + (size_t)base*3;
    for (int i = t; i < 2048*3; i += 256) cbuf[i] = gsrc[i];
    __syncthreads();
    #pragma unroll 8
    for (int j = 0; j < 32; ++j) {
      int i = lane + 64*j;
      float dx = qx - cbuf[i*3];
      float dy = qy - cbuf[i*3+1];
      float dz = qz - cbuf[i*3+2];
      float d2 = fmaf(dx, dx, fmaf(dy, dy, dz*dz));
      if (d2 <= R2F) {
        unsigned int pos = atomicAdd(&scnt[w], 1u);
        if (pos < SCAP)
          surv[w][pos] = ((unsigned long long)__float_as_uint(d2) << 32)
                         | (unsigned int)(base + i);
      }
    }
  }
  __syncthreads();
  int C = (int)scnt[w]; if (C > SCAP) C = SCAP;
  unsigned long long k0 = (lane      < C) ? surv[w][lane]      : ~0ULL;
  unsigned long long k1 = (lane + 64 < C) ? surv[w][lane + 64] : ~0ULL;
  int r0 = 0, r1 = 0;
  for (int j = 0; j < C; ++j) {
    unsigned long long kj = surv[w][j];       // same addr all lanes: broadcast
    r0 += (kj < k0);
    r1 += (kj < k1);
  }
  size_t g = (size_t)cloud*NPTS + q;
  if (k0 != ~0ULL && r0 < KNN) fidx[g*KNN + r0] = (short)(k0 & 0xffffu);
  if (k1 != ~0ULL && r1 < KNN) fidx[g*KNN + r1] = (short)(k1 & 0xffffu);
  if (lane >= C && lane < KNN) fidx[g*KNN + lane] = (short)-1;  // sentinel fill
}

// ---- fused KPConv, 4 points/block ---------------------------------------------
// Phase A (per wave = per point): agg[pt][j=p*64+c] in LDS.
// Phase B: contraction h2 = agg @ Wkp; W_kp chunk shared by all 4 points.
// LDS 39.5 KB (red_s overlaid on w_s) -> 4 blocks/CU.
// idx_s[w]/w_s[w] are wave-private: no block barrier needed around them.
__global__ __launch_bounds__(256) void kpconv_fused(
    const float* __restrict__ cA, const float* __restrict__ cB,
    const float* __restrict__ kpts, const short* __restrict__ fidx,
    const float* __restrict__ h, const float* __restrict__ Wkp,
    float* __restrict__ h2)
{
  __shared__ float wkp_s[64*64];        // 16 KB: 64-row chunk of W_kp
  __shared__ float wr_s[NT][KNN*16];    // 8 KB: Phase A w; reused as red_s later
  __shared__ float agg_s[NT][KPN*SCC];  // 15 KB, j = p*64+c
  __shared__ int   idx_s[NT][KNN];      // 512 B
  float (*red_s)[NT*SCC] = (float(*)[NT*SCC])wr_s;   // overlay (epilogue only)
  int t = threadIdx.x;
  int w = t >> 6, lane = t & 63;
  int gq = blockIdx.x*NT + w;           // 0..16383 = cloud*NPTS + n
  int cloud = gq >> 13, n = gq & 8191;
  const float* coords = cloud ? cB : cA;
  if (lane < KNN) idx_s[w][lane] = fidx[(size_t)gq*KNN + lane];
  // (no barrier: idx_s[w] is wave-private)
  float qx = coords[(size_t)n*3];
  float qy = coords[(size_t)n*3+1];
  float qz = coords[(size_t)n*3+2];
  for (int e = lane; e < KNN*16; e += 64) {
    int k = e >> 4, p = e & 15;
    int idx = idx_s[w][k];
    float wv = 0.f;
    if (idx >= 0 && p < KPN) {
      float rx = coords[(size_t)idx*3]   - qx;
      float ry = coords[(size_t)idx*3+1] - qy;
      float rz = coords[(size_t)idx*3+2] - qz;
      float dx = rx - kpts[(size_t)p*3];
      float dy = ry - kpts[(size_t)p*3+1];
      float dz = rz - kpts[(size_t)p*3+2];
      float d = sqrtf(fmaf(dx, dx, fmaf(dy, dy, dz*dz)));
      wv = fmaxf(1.0f - d*INV_EXT, 0.0f);
    }
    wr_s[w][k*16 + p] = wv;
  }
  // (no barrier: wr_s[w] is wave-private)
  // Phase A: agg[p][c] for c = lane (acc[15] is a dummy)
  float acc[16];
  #pragma unroll
  for (int p = 0; p < 16; ++p) acc[p] = 0.f;
  for (int k = 0; k < KNN; ++k) {
    int idx = idx_s[w][k];                // wave-uniform
    if (idx < 0) continue;
    float f = h[((size_t)(cloud*NPTS + idx))*SCC + lane];
    const float4* wr = (const float4*)&wr_s[w][k*16];
    #pragma unroll
    for (int g = 0; g < 4; ++g) {
      float4 w4 = wr[g];
      acc[g*4+0] = fmaf(w4.x, f, acc[g*4+0]);
      acc[g*4+1] = fmaf(w4.y, f, acc[g*4+1]);
      acc[g*4+2] = fmaf(w4.z, f, acc[g*4+2]);
      acc[g*4+3] = fmaf(w4.w, f, acc[g*4+3]);
    }
  }
  #pragma unroll
  for (int p = 0; p < KPN; ++p) agg_s[w][p*SCC + lane] = acc[p];
  // Phase B: shared-W contraction (first chunk's barrier publishes agg_s)
  int jg = lane >> 4;            // 0..3
  int dq = (lane & 15) * 4;      // dim group
  float4 acc4[NT];
  #pragma unroll
  for (int pt = 0; pt < NT; ++pt) acc4[pt] = make_float4(0.f,0.f,0.f,0.f);
  for (int c0 = 0; c0 < KPN*SCC; c0 += 64) {
    __syncthreads();
    {
      const float4* gsrc = (const float4*)(Wkp + (size_t)c0*64);
      float4* ldst = (float4*)wkp_s;
      ldst[t]       = gsrc[t];
      ldst[t + 256] = gsrc[t + 256];
      ldst[t + 512] = gsrc[t + 512];
      ldst[t + 768] = gsrc[t + 768];
    }
    __syncthreads();
    int jbase = w*16 + jg*4;     // local row base within chunk
    float4 wv[4];
    #pragma unroll
    for (int g = 0; g < 4; ++g)
      wv[g] = *(const float4*)&wkp_s[(jbase + g)*64 + dq];
    #pragma unroll
    for (int pt = 0; pt < NT; ++pt) {
      float4 av = *(const float4*)&agg_s[pt][c0 + jbase];
      float a[4] = {av.x, av.y, av.z, av.w};
      #pragma unroll
      for (int g = 0; g < 4; ++g) {
        acc4[pt].x = fmaf(a[g], wv[g].x, acc4[pt].x);
        acc4[pt].y = fmaf(a[g], wv[g].y, acc4[pt].y);
        acc4[pt].z = fmaf(a[g], wv[g].z, acc4[pt].z);
        acc4[pt].w = fmaf(a[g], wv[g].w, acc4[pt].w);
      }
    }
  }
  // reduce over jg lane-groups (bits 4,5 of lane)
  #pragma unroll
  for (int pt = 0; pt < NT; ++pt) {
    acc4[pt].x += __shfl_xor(acc4[pt].x, 16); acc4[pt].x += __shfl_xor(acc4[pt].x, 32);
    acc4[pt].y += __shfl_xor(acc4[pt].y, 16); acc4[pt].y += __shfl_xor(acc4[pt].y, 32);
    acc4[pt].z += __shfl_xor(acc4[pt].z, 16); acc4[pt].z += __shfl_xor(acc4[pt].z, 32);
    acc4[pt].w += __shfl_xor(acc4[pt].w, 16); acc4[pt].w += __shfl_xor(acc4[pt].w, 32);
  }
  __syncthreads();     // w_s reads all done; safe to overlay red_s
  if (lane < 16) {
    #pragma unroll
    for (int pt = 0; pt < NT; ++pt)
      *(float4*)&red_s[w][pt*SCC + dq] = acc4[pt];
  }
  __syncthreads();
  {
    int pt = t >> 6, d = t & 63;     // one output element per thread
    float s = red_s[0][pt*SCC + d] + red_s[1][pt*SCC + d]
            + red_s[2][pt*SCC + d] + red_s[3][pt*SCC + d];
    h2[((size_t)blockIdx.x*NT + pt)*SCC + d] = s;
  }
}

// ---- conv_out: one thread per (cloud,n,d), f32 out ---------------------------
__global__ __launch_bounds__(256) void conv_out_naive(
    const float* __restrict__ h2, const float* __restrict__ W,
    const float* __restrict__ b, float* __restrict__ y)
{
  size_t e = (size_t)blockIdx.x*256 + threadIdx.x;   // < 2*8192*256 = 2^22
  int d = (int)(e & 255);
  size_t nrow = e >> 8;            // cloud*8192 + n
  float acc = b[d];
  const float* hr = h2 + nrow*SCC;
  #pragma unroll 8
  for (int c = 0; c < SCC; ++c)
    acc = fmaf(hr[c], W[(size_t)c*256 + d], acc);
  y[e] = acc;
}

// ---- BN ----------------------------------------------------------------------
__global__ __launch_bounds__(256) void bn_stats_k(
    const float* __restrict__ y, float* __restrict__ stats)
{
  int b = blockIdx.x;          // 512 blocks: cloud(1)|rb(8), 32 rows each
  int cloud = b >> 8, rb = b & 255;
  int c = threadIdx.x;
  size_t base = ((size_t)(cloud*NPTS + rb*32))*OUTC + c;
  float s = 0.f, s2 = 0.f;
  for (int r = 0; r < 32; ++r) {
    float v = y[base + (size_t)r*OUTC];
    s += v; s2 = fmaf(v, v, s2);
  }
  atomicAdd(&stats[cloud*512 + c], s);
  atomicAdd(&stats[cloud*512 + 256 + c], s2);
}

__global__ __launch_bounds__(256) void bn_apply_k(
    float* __restrict__ y, const float* __restrict__ stats,
    const float* __restrict__ gamma, const float* __restrict__ beta)
{
  size_t e = (size_t)blockIdx.x*256 + threadIdx.x;
  int c = (int)(e & 255);
  int cloud = (int)(e >> 21);
  float s  = stats[cloud*512 + c];
  float s2 = stats[cloud*512 + 256 + c];
  float mu  = s * (1.0f/NPTS);
  float var = fmaxf(s2 * (1.0f/NPTS) - mu*mu, 0.f);
  float sc = gamma[c] * rsqrtf(var + 1e-5f);
  float sh = beta[c] - mu*sc;
  float v = fmaf(y[e], sc, sh);
  v = v > 0.f ? v : 0.1f*v;
  y[e] = v;
}

// ---- coords tail of output (f32) + stats zeroing (block 192) -----------------
__global__ __launch_bounds__(256) void emit_coords(
    const float* __restrict__ scd, const float* __restrict__ tcd,
    float* __restrict__ out, float* __restrict__ stats)
{
  int b = blockIdx.x;
  int t = threadIdx.x;
  if (b == 192) {
    for (int i = t; i < 1024; i += 256) stats[i] = 0.f;
    return;
  }
  int i = b*256 + t;    // 0..49151
  out[i] = (i < NPTS*3) ? scd[i] : tcd[i - NPTS*3];
}

extern "C" void kernel_launch(void* const* d_in, const int* in_sizes, int n_in,
                              void* d_out, int out_size, void* d_ws, size_t ws_size,
                              hipStream_t stream)
{
  (void)in_sizes; (void)n_in; (void)out_size; (void)ws_size;
  const float* src   = (const float*)d_in[0];
  const float* tgt   = (const float*)d_in[1];
  const float* scd   = (const float*)d_in[2];
  const float* tcd   = (const float*)d_in[3];
  const float* W_in  = (const float*)d_in[4];
  const float* b_in  = (const float*)d_in[5];
  const float* kpts  = (const float*)d_in[6];
  const float* W_kp  = (const float*)d_in[7];
  const float* W_out = (const float*)d_in[8];
  const float* b_out = (const float*)d_in[9];
  const float* gamma = (const float*)d_in[10];
  const float* beta  = (const float*)d_in[11];

  // ---- workspace (peak ~9.0 MB) ----
  char* ws = (char*)d_ws;
  float* h     = (float*)ws;                        // 0..4 MB  [2][8192][64]
  float* h2    = (float*)(ws + (4u<<20));           // 4..8 MB
  short* fidx  = (short*)(ws + (8u<<20));           // 8..9 MB [16384][32] i16
  float* stats = (float*)(ws + (9u<<20));           // 4 KB

  float* yout = (float*)d_out;

  emit_coords<<<193, 256, 0, stream>>>(scd, tcd, yout + (size_t)2*NPTS*OUTC, stats);
  knn_par<<<4096, 256, 0, stream>>>(scd, tcd, fidx);
  conv_in_naive<<<4096, 256, 0, stream>>>(src, tgt, W_in, b_in, h);
  kpconv_fused<<<4096, 256, 0, stream>>>(scd, tcd, kpts, fidx, h, W_kp, h2);
  conv_out_naive<<<16384, 256, 0, stream>>>(h2, W_out, b_out, yout);
  bn_stats_k<<<512, 256, 0, stream>>>(yout, stats);
  bn_apply_k<<<16384, 256, 0, stream>>>(yout, stats, gamma, beta);
}